// Round 8
// baseline (281.296 us; speedup 1.0000x reference)
//
#include <hip/hip_runtime.h>
#include <math.h>

#define N_NODES 4096
#define NHEADS  4
#define NSPLIT  4
#define KVRANGE 1024   // 4096 / NSPLIT

typedef _Float16 f16;
typedef _Float16 half8 __attribute__((ext_vector_type(8)));
typedef float f32x4 __attribute__((ext_vector_type(4)));

// ---------------------------------------------------------------- GEMM body (f16 in, f32 acc)
// out[m][j] = sum_k A[m][k] * B[j][k] (+ bias) ; A [M][K], B [J][K] f16, K % 64 == 0
// EPI: 0 f16 out, col-bias, *alpha   1 f16 out, col-bias, relu
//      2 f16 out, row-bias           3 f32 out, col-bias, + resid + c2n[lab[m]]
template <int EPI>
__device__ __forceinline__ void gemm_body(const f16* __restrict__ A,
                                          const f16* __restrict__ B,
                                          const float* __restrict__ bias,
                                          const float* __restrict__ resid,
                                          const int* __restrict__ lab,
                                          const float* __restrict__ c2n,
                                          void* __restrict__ outv,
                                          int M, int K, int J, float alpha,
                                          int bx, int by, f16* smem) {
  f16* As = smem;             // 64 rows x 128B, XOR-swizzled chunks
  f16* Bs = smem + 64 * 64;
  const int t  = threadIdx.x;
  const int mb = bx * 64, jb = by * 64;
  const int w  = t >> 6, l = t & 63;
  const int g_ = l >> 4, c_ = l & 15;
  const int m0 = (w >> 1) * 32, n0 = (w & 1) * 32;

  f32x4 acc[2][2];
#pragma unroll
  for (int i = 0; i < 2; ++i)
#pragma unroll
    for (int j = 0; j < 2; ++j) acc[i][j] = (f32x4){0.f, 0.f, 0.f, 0.f};

#define FRAG16(BUF, row, kh) \
  (*(const half8*)&BUF[(size_t)(row) * 64 + (((((kh) * 4 + g_) ^ (c_ & 7))) << 3)])

  for (int kb = 0; kb < K; kb += 64) {
    __syncthreads();
#pragma unroll
    for (int i = 0; i < 2; ++i) {
      int f = t + i * 256;            // 512 uint4 per matrix tile
      int r = f >> 3, ch = f & 7;
      *(uint4*)&As[r * 64 + ((ch ^ (r & 7)) << 3)] =
          *(const uint4*)&A[(size_t)(mb + r) * K + kb + ch * 8];
      *(uint4*)&Bs[r * 64 + ((ch ^ (r & 7)) << 3)] =
          *(const uint4*)&B[(size_t)(jb + r) * K + kb + ch * 8];
    }
    __syncthreads();
#pragma unroll
    for (int kh = 0; kh < 2; ++kh) {
      half8 a0 = FRAG16(As, m0 + c_, kh);
      half8 a1 = FRAG16(As, m0 + 16 + c_, kh);
      half8 b0 = FRAG16(Bs, n0 + c_, kh);
      half8 b1 = FRAG16(Bs, n0 + 16 + c_, kh);
      acc[0][0] = __builtin_amdgcn_mfma_f32_16x16x32_f16(a0, b0, acc[0][0], 0, 0, 0);
      acc[0][1] = __builtin_amdgcn_mfma_f32_16x16x32_f16(a0, b1, acc[0][1], 0, 0, 0);
      acc[1][0] = __builtin_amdgcn_mfma_f32_16x16x32_f16(a1, b0, acc[1][0], 0, 0, 0);
      acc[1][1] = __builtin_amdgcn_mfma_f32_16x16x32_f16(a1, b1, acc[1][1], 0, 0, 0);
    }
  }
#undef FRAG16

#pragma unroll
  for (int mt = 0; mt < 2; ++mt)
#pragma unroll
    for (int nt = 0; nt < 2; ++nt) {
      int mbase = mb + m0 + mt * 16 + g_ * 4;
      int jj    = jb + n0 + nt * 16 + c_;
      if (EPI == 0 || EPI == 1) {
        f16* out = (f16*)outv;
        float bc = bias[jj];
#pragma unroll
        for (int r = 0; r < 4; ++r) {
          float v = (acc[mt][nt][r] + bc) * alpha;
          if (EPI == 1) v = fmaxf(v, 0.f);
          out[(size_t)(mbase + r) * J + jj] = (f16)v;
        }
      } else if (EPI == 2) {
        f16* out = (f16*)outv;
#pragma unroll
        for (int r = 0; r < 4; ++r)
          out[(size_t)(mbase + r) * J + jj] = (f16)(acc[mt][nt][r] + bias[mbase + r]);
      } else {
        float* out = (float*)outv;
        float bc = bias[jj];
#pragma unroll
        for (int r = 0; r < 4; ++r) {
          int m = mbase + r;
          out[(size_t)m * J + jj] = acc[mt][nt][r] + bc +
              resid[(size_t)m * J + jj] + c2n[lab[m] * 128 + jj];
        }
      }
    }
}

template <int EPI>
__global__ __launch_bounds__(256) void k_gemm16(const f16* __restrict__ A,
                                                const f16* __restrict__ B,
                                                const float* __restrict__ bias,
                                                const float* __restrict__ resid,
                                                const int* __restrict__ lab,
                                                const float* __restrict__ c2n,
                                                void* __restrict__ outv,
                                                int M, int K, int J, float alpha) {
  __shared__ f16 smem[2 * 64 * 64];
  gemm_body<EPI>(A, B, bias, resid, lab, c2n, outv, M, K, J, alpha,
                 blockIdx.x, blockIdx.y, smem);
}

// ---------------------------------------------------------------- prep: combined + w2h + zero
// pool: [Wq 32768][Wk 32768][Wv 262144][W1 262144][W2 65536] = 655360
__global__ __launch_bounds__(256) void k_prep(const float* __restrict__ x,
                                              const float* __restrict__ h,
                                              const float* __restrict__ Wq,
                                              const float* __restrict__ Wk,
                                              const float* __restrict__ Wv,
                                              const float* __restrict__ W1,
                                              const float* __restrict__ W2,
                                              f16* __restrict__ comb16,
                                              f16* __restrict__ pool,
                                              float* __restrict__ sums) {
  const int b = blockIdx.x, t = threadIdx.x;
  if (b < 1024) {                      // combined = [x, h] -> f16
    int i = b * 256 + t;               // over N*64 float4
    int n = i >> 6, c = i & 63;
    float4 v;
    if (c < 32) v = ((const float4*)x)[n * 32 + c];
    else        v = ((const float4*)h)[n * 32 + (c - 32)];
    union { uint2 u; f16 h4[4]; } pk;
    pk.h4[0] = (f16)v.x; pk.h4[1] = (f16)v.y; pk.h4[2] = (f16)v.z; pk.h4[3] = (f16)v.w;
    *(uint2*)&comb16[(size_t)i * 4] = pk.u;
  } else if (b < 1664) {               // weights -> f16
    int i4 = ((b - 1024) * 256 + t) * 4;
    const float* src; int off;
    if      (i4 <  32768) { src = Wq; off = 0; }
    else if (i4 <  65536) { src = Wk; off = 32768; }
    else if (i4 < 327680) { src = Wv; off = 65536; }
    else if (i4 < 589824) { src = W1; off = 327680; }
    else                  { src = W2; off = 589824; }
    float4 v = *(const float4*)&src[i4 - off];
    union { uint2 u; f16 h4[4]; } pk;
    pk.h4[0] = (f16)v.x; pk.h4[1] = (f16)v.y; pk.h4[2] = (f16)v.z; pk.h4[3] = (f16)v.w;
    *(uint2*)&pool[i4] = pk.u;
  } else {                             // zero sums[8192] + cnt[64] (contiguous)
    int i = (b - 1664) * 256 + t;
    if (i < 8256) sums[i] = 0.f;
  }
}

// ---------------------------------------------------------------- qkv: V-proj | Q-proj | K-proj | segsum
__global__ __launch_bounds__(256) void k_qkv(const f16* __restrict__ comb16,
                                             const f16* __restrict__ wq16,
                                             const f16* __restrict__ wk16,
                                             const f16* __restrict__ wv16,
                                             const float* __restrict__ bq,
                                             const float* __restrict__ bk,
                                             const float* __restrict__ bv,
                                             f16* __restrict__ qf16,
                                             f16* __restrict__ kf16,
                                             f16* __restrict__ vt16,
                                             const float* __restrict__ h,
                                             const int* __restrict__ lab,
                                             float* __restrict__ sums,
                                             float* __restrict__ cnt,
                                             float qscale) {
  __shared__ f16 smem[2 * 64 * 64];
  const int b = blockIdx.x;
  if (b < 1024) {            // V^T: A = Wv [1024][256], B = comb -> vt [1024][4096]
    gemm_body<2>(wv16, comb16, bv, nullptr, nullptr, nullptr, vt16,
                 1024, 256, 4096, 1.0f, b & 15, b >> 4, smem);
  } else if (b < 1152) {     // Q (pre-scaled)
    int r = b - 1024;
    gemm_body<0>(comb16, wq16, bq, nullptr, nullptr, nullptr, qf16,
                 4096, 256, 128, qscale, r & 63, r >> 6, smem);
  } else if (b < 1280) {     // K
    int r = b - 1152;
    gemm_body<0>(comb16, wk16, bk, nullptr, nullptr, nullptr, kf16,
                 4096, 256, 128, 1.0f, r & 63, r >> 6, smem);
  } else {                   // segment sum over h
    int i = (b - 1280) * 256 + threadIdx.x;   // N*128
    int n = i >> 7, d = i & 127;
    int c = lab[n];
    atomicAdd(&sums[c * 128 + d], h[i]);
    if (d == 0) atomicAdd(&cnt[c], 1.0f);
  }
}

// ---------------------------------------------------------------- MFMA flash attention (L2-direct)
// K/V MFMA fragments load straight from global (per-(head,split) slices are L2-resident;
// XCD-aware block decode pins each combo's 64 q-blocks to one XCD). LDS holds only P.
// qg,kg: f16 [N][128] (col = h*32+e, q pre-scaled by 1/sqrt(32))
// vt:    f16 [H*256][4096] (V transposed)
// Partials: pO f16 [s][1024 j][4096 q] (normalized), pM/pL f32 [s][4][4096]
__global__ __launch_bounds__(256, 4) void k_attn_mfma(const f16* __restrict__ qg,
                                                      const f16* __restrict__ kg,
                                                      const f16* __restrict__ vt,
                                                      f16* __restrict__ pO,
                                                      float* __restrict__ pM,
                                                      float* __restrict__ pL) {
  // XCD-aware decode: combo (hd,sp) -> one XCD (blocks dispatch round-robin over 8 XCDs)
  const int b     = blockIdx.x;          // 0..1023
  const int xcd   = b & 7;
  const int i_    = b >> 3;              // 0..127
  const int combo = xcd * 2 + (i_ >> 6); // 0..15
  const int qblk  = i_ & 63;
  const int hd    = combo >> 2, sp = combo & 3;
  const int kv0   = sp * KVRANGE;
  const int qb    = qblk * 64;

  const int t = threadIdx.x;
  const int w = t >> 6, l = t & 63;
  const int g = l >> 4, c = l & 15;

  __shared__ f16 Ps[64 * 40];          // [q][kv] pad 40 (B-frag layout)
  __shared__ float CfS[64];            // per-q rescale factor (then final l)

  // Q fragment for this wave's q-group (q = qb + w*16 + c)
  half8 qf = *(const half8*)&qg[(size_t)(qb + w * 16 + c) * 128 + hd * 32 + g * 8];

  // base pointers for this lane's fragment rows
  const f16* kbase = &kg[(size_t)(kv0)*128 + hd * 32 + g * 8];           // + (kb+row)*128
  const f16* vbase = &vt[(size_t)(hd * 256) * 4096 + kv0 + g * 8];       // + d*4096 + kb

  f32x4 oacc[4][4];                    // [dt_local][qt]; d = (w*4+i)*16+g*4+r, q = qb+qt*16+c
#pragma unroll
  for (int i = 0; i < 4; ++i)
#pragma unroll
    for (int j = 0; j < 4; ++j) oacc[i][j] = (f32x4){0.f, 0.f, 0.f, 0.f};
  float m_run = -INFINITY, l_run = 0.f;
  const f32x4 zero4 = {0.f, 0.f, 0.f, 0.f};

  for (int kb = 0; kb < KVRANGE; kb += 32) {
    __syncthreads();   // prev PV / CfS reads complete before Ps/CfS are overwritten

    // issue all global fragment loads up front (independent; V consumed after barrier)
    half8 kf0 = *(const half8*)&kbase[(size_t)(kb + c) * 128];
    half8 kf1 = *(const half8*)&kbase[(size_t)(kb + 16 + c) * 128];
    half8 vfr[4];
#pragma unroll
    for (int i = 0; i < 4; ++i)
      vfr[i] = *(const half8*)&vbase[(size_t)((w * 4 + i) * 16 + c) * 4096 + kb];

    // ---- QK^T for this wave's 16 q (swapped: S^T tile, lane reg r -> kv = g*4+r / +16)
    f32x4 s0 = __builtin_amdgcn_mfma_f32_16x16x32_f16(kf0, qf, zero4, 0, 0, 0);
    f32x4 s1 = __builtin_amdgcn_mfma_f32_16x16x32_f16(kf1, qf, zero4, 0, 0, 0);

    float sv[8];
#pragma unroll
    for (int r = 0; r < 4; ++r) {
      float a = s0[r]; sv[r]     = a > 0.f ? a : 0.2f * a;   // leaky(0.2), scale in q
      float b2 = s1[r]; sv[4 + r] = b2 > 0.f ? b2 : 0.2f * b2;
    }
    float mx = sv[0];
#pragma unroll
    for (int r = 1; r < 8; ++r) mx = fmaxf(mx, sv[r]);
    mx = fmaxf(mx, __shfl_xor(mx, 16));
    mx = fmaxf(mx, __shfl_xor(mx, 32));

    float cf = 1.f;
    if (!__all(mx <= m_run + 8.f)) {   // defer-max
      float m_new = fmaxf(m_run, mx);
      cf = __expf(m_run - m_new);
      m_run = m_new;
    }
    float p[8], ps = 0.f;
#pragma unroll
    for (int r = 0; r < 8; ++r) { p[r] = __expf(sv[r] - m_run); ps += p[r]; }
    ps += __shfl_xor(ps, 16);
    ps += __shfl_xor(ps, 32);
    l_run = l_run * cf + ps;

    if (g == 0) CfS[w * 16 + c] = cf;
    // pack P -> Ps[q][kv] (pairs are kv-consecutive: reg r -> kv g*4+r, +16)
    {
      union { unsigned u; f16 h2[2]; } z;
      uint2 lo, hi;
      z.h2[0] = (f16)p[0]; z.h2[1] = (f16)p[1]; lo.x = z.u;
      z.h2[0] = (f16)p[2]; z.h2[1] = (f16)p[3]; lo.y = z.u;
      z.h2[0] = (f16)p[4]; z.h2[1] = (f16)p[5]; hi.x = z.u;
      z.h2[0] = (f16)p[6]; z.h2[1] = (f16)p[7]; hi.y = z.u;
      *(uint2*)&Ps[(w * 16 + c) * 40 + g * 4]      = lo;
      *(uint2*)&Ps[(w * 16 + c) * 40 + 16 + g * 4] = hi;
    }
    __syncthreads();   // P + Cf ready

    // ---- rescale accumulators by per-q cf
#pragma unroll
    for (int qt = 0; qt < 4; ++qt) {
      float cfq = CfS[qt * 16 + c];
      if (!__all(cfq == 1.f)) {
#pragma unroll
        for (int i = 0; i < 4; ++i) {
          oacc[i][qt][0] *= cfq; oacc[i][qt][1] *= cfq;
          oacc[i][qt][2] *= cfq; oacc[i][qt][3] *= cfq;
        }
      }
    }
    // ---- PV: this wave's d-slice (dt = w*4+i), all 4 q-tiles
    half8 pfr[4];
#pragma unroll
    for (int qt = 0; qt < 4; ++qt)
      pfr[qt] = *(const half8*)&Ps[(qt * 16 + c) * 40 + g * 8];
    __builtin_amdgcn_s_setprio(1);
#pragma unroll
    for (int i = 0; i < 4; ++i) {
#pragma unroll
      for (int qt = 0; qt < 4; ++qt)
        oacc[i][qt] = __builtin_amdgcn_mfma_f32_16x16x32_f16(vfr[i], pfr[qt], oacc[i][qt], 0, 0, 0);
    }
    __builtin_amdgcn_s_setprio(0);
  }

  // broadcast final l per q, then write normalized partials
  __syncthreads();
  if (g == 0) CfS[w * 16 + c] = l_run;
  __syncthreads();
  float linv[4];
#pragma unroll
  for (int qt = 0; qt < 4; ++qt) linv[qt] = 1.f / CfS[qt * 16 + c];
#pragma unroll
  for (int i = 0; i < 4; ++i)
#pragma unroll
    for (int qt = 0; qt < 4; ++qt)
#pragma unroll
      for (int r = 0; r < 4; ++r) {
        int j = hd * 256 + (w * 4 + i) * 16 + g * 4 + r;
        pO[(size_t)(sp * 1024 + j) * 4096 + qb + qt * 16 + c] =
            (f16)(oacc[i][qt][r] * linv[qt]);
      }
  if (g == 0) {
    pM[(sp * 4 + hd) * 4096 + qb + w * 16 + c] = m_run;
    pL[(sp * 4 + hd) * 4096 + qb + w * 16 + c] = l_run;
  }
}

// ---------------------------------------------------------------- merge + fused GRU->c2n
__global__ __launch_bounds__(256) void k_mergeplus(const f16* __restrict__ pO,
                                                   const float* __restrict__ pM,
                                                   const float* __restrict__ pL,
                                                   f16* __restrict__ hp,
                                                   const float* __restrict__ sums,
                                                   const float* __restrict__ cnt,
                                                   const float* __restrict__ ch,
                                                   const float* __restrict__ gWih,
                                                   const float* __restrict__ gbih,
                                                   const float* __restrict__ gWhh,
                                                   const float* __restrict__ gbhh,
                                                   const float* __restrict__ Wp,
                                                   const float* __restrict__ bp,
                                                   float* __restrict__ out_uch,
                                                   float* __restrict__ c2n) {
  const int b = blockIdx.x, t = threadIdx.x;
  if (b < 1024) {                       // ---- split-K merge -> hp16 [4096][1024]
    __shared__ float wm[NSPLIT][64], wl[NSPLIT][64];
    __shared__ float tile[64][65];
    const int q0 = (b & 63) * 64, jb = (b >> 6) * 64;
    const int h  = jb >> 8;

    if (t < 64) {
#pragma unroll
      for (int s = 0; s < NSPLIT; ++s) {
        wm[s][t] = pM[(s * 4 + h) * 4096 + q0 + t];
        wl[s][t] = pL[(s * 4 + h) * 4096 + q0 + t];
      }
    }
    __syncthreads();

    const int q8 = (t & 7) * 8;
#pragma unroll
    for (int it = 0; it < 2; ++it) {
      int jl = (t >> 3) + it * 32;
      float wgt[NSPLIT][8], inv[8];
#pragma unroll
      for (int q = 0; q < 8; ++q) {
        float M = wm[0][q8 + q];
#pragma unroll
        for (int s = 1; s < NSPLIT; ++s) M = fmaxf(M, wm[s][q8 + q]);
        float den = 0.f;
#pragma unroll
        for (int s = 0; s < NSPLIT; ++s) {
          float wv = wl[s][q8 + q] * __expf(wm[s][q8 + q] - M);
          wgt[s][q] = wv; den += wv;
        }
        inv[q] = 1.f / den;
      }
      float o[8] = {0.f};
#pragma unroll
      for (int s = 0; s < NSPLIT; ++s) {
        union { uint4 u; f16 h8[8]; } raw;
        raw.u = *(const uint4*)&pO[(size_t)(s * 1024 + jb + jl) * 4096 + q0 + q8];
#pragma unroll
        for (int q = 0; q < 8; ++q) o[q] += wgt[s][q] * (float)raw.h8[q];
      }
#pragma unroll
      for (int q = 0; q < 8; ++q) tile[q8 + q][jl] = o[q] * inv[q];
    }
    __syncthreads();

#pragma unroll
    for (int it = 0; it < 2; ++it) {
      int ql = (t >> 3) + it * 32, chk = t & 7;
      union { uint4 u; f16 h8[8]; } pk;
#pragma unroll
      for (int k = 0; k < 8; ++k) pk.h8[k] = (f16)tile[ql][chk * 8 + k];
      *(uint4*)&hp[(size_t)(q0 + ql) * 1024 + jb + chk * 8] = pk.u;
    }
  } else {                              // ---- GRU + c2n, 2 clusters per block
    __shared__ float ax[2][128], hx[2][128], ul[2][128];
    const int cc = t >> 7, d = t & 127;
    const int c  = (b - 1024) * 2 + cc;
    float count = cnt[c];
    ax[cc][d] = sums[c * 128 + d] / fmaxf(count, 1.0f);
    hx[cc][d] = ch[c * 128 + d];
    __syncthreads();
    float gi[3], gh[3];
#pragma unroll
    for (int g = 0; g < 3; ++g) {
      const float4* wi4 = (const float4*)&gWih[(size_t)(g * 128 + d) * 128];
      const float4* wh4 = (const float4*)&gWhh[(size_t)(g * 128 + d) * 128];
      float si = 0.f, sh = 0.f;
#pragma unroll 8
      for (int e = 0; e < 32; ++e) {
        float4 wv = wi4[e], hv = wh4[e];
        si = fmaf(ax[cc][e*4+0], wv.x, si); si = fmaf(ax[cc][e*4+1], wv.y, si);
        si = fmaf(ax[cc][e*4+2], wv.z, si); si = fmaf(ax[cc][e*4+3], wv.w, si);
        sh = fmaf(hx[cc][e*4+0], hv.x, sh); sh = fmaf(hx[cc][e*4+1], hv.y, sh);
        sh = fmaf(hx[cc][e*4+2], hv.z, sh); sh = fmaf(hx[cc][e*4+3], hv.w, sh);
      }
      gi[g] = si + gbih[g * 128 + d];
      gh[g] = sh + gbhh[g * 128 + d];
    }
    float r = 1.f / (1.f + expf(-(gi[0] + gh[0])));
    float z = 1.f / (1.f + expf(-(gi[1] + gh[1])));
    float nn = tanhf(gi[2] + r * gh[2]);
    float hv = hx[cc][d];
    float nh = (1.f - z) * nn + z * hv;
    float res = (count > 0.f) ? nh : hv;
    ul[cc][d] = res;
    out_uch[c * 128 + d] = res;
    __syncthreads();
    const float4* w4 = (const float4*)&Wp[(size_t)d * 128];
    float s = 0.f;
#pragma unroll 8
    for (int e = 0; e < 32; ++e) {
      float4 wv = w4[e];
      s = fmaf(ul[cc][e*4+0], wv.x, s); s = fmaf(ul[cc][e*4+1], wv.y, s);
      s = fmaf(ul[cc][e*4+2], wv.z, s); s = fmaf(ul[cc][e*4+3], wv.w, s);
    }
    c2n[c * 128 + d] = s + bp[d];
  }
}

// ---------------------------------------------------------------- launch
extern "C" void kernel_launch(void* const* d_in, const int* in_sizes, int n_in,
                              void* d_out, int out_size, void* d_ws, size_t ws_size,
                              hipStream_t stream) {
  const float* x    = (const float*)d_in[0];
  const float* h    = (const float*)d_in[1];
  const float* ch   = (const float*)d_in[2];
  const int*   lab  = (const int*)d_in[4];
  const float* Wq   = (const float*)d_in[8];
  const float* bq   = (const float*)d_in[9];
  const float* Wk   = (const float*)d_in[10];
  const float* bk   = (const float*)d_in[11];
  const float* Wv   = (const float*)d_in[12];
  const float* bv   = (const float*)d_in[13];
  const float* W1   = (const float*)d_in[14];
  const float* b1   = (const float*)d_in[15];
  const float* W2   = (const float*)d_in[16];
  const float* b2   = (const float*)d_in[17];
  const float* gWih = (const float*)d_in[18];
  const float* gbih = (const float*)d_in[19];
  const float* gWhh = (const float*)d_in[20];
  const float* gbhh = (const float*)d_in[21];
  const float* Wp   = (const float*)d_in[22];
  const float* bp   = (const float*)d_in[23];

  float* outp    = (float*)d_out;                 // [4096*128] updated_h
  float* out_uch = outp + 4096 * 128;             // [64*128] updated_cluster_h

  // ---- workspace layout
  f16* comb16 = (f16*)d_ws;                        // 4096*256
  f16* w16    = comb16 + 4096 * 256;               // 655360
  f16* wq16   = w16;                               //  32768
  f16* wk16   = w16 + 32768;
  f16* wv16   = w16 + 65536;                       // 262144 [1024][256]
  f16* w116   = w16 + 327680;                      // 262144 [256][1024]
  f16* w216   = w16 + 589824;                      //  65536 [256][256]
  f16* qf16   = w16 + 655360;                      // 4096*128
  f16* kf16   = qf16 + 4096 * 128;                 // 4096*128
  f16* vt16   = kf16 + 4096 * 128;                 // 1024*4096
  f16* pO     = vt16 + 1024 * 4096;                // 4*1024*4096
  f16* hp16   = pO + (size_t)NSPLIT * 1024 * 4096; // 4096*1024
  f16* y116   = hp16 + (size_t)4096 * 1024;        // 4096*256
  float* pM   = (float*)(y116 + 4096 * 256);       // 4*4*4096
  float* pL   = pM + NSPLIT * 4 * 4096;
  float* sums = pL + NSPLIT * 4 * 4096;            // 8192 (+64 cnt contiguous)
  float* cnt  = sums + 64 * 128;                   // 64
  float* c2n  = cnt + 64;                          // 8192

  const float qscale = 0.17677669529663687f;       // 1/sqrt(32)

  // 1) combined(f16) + weights->f16 + zero(sums,cnt)
  k_prep<<<1697, 256, 0, stream>>>(x, h, Wq, Wk, Wv, W1, W2, comb16, w16, sums);
  // 2) V^T | Q | K projections + segsum, all concurrent
  k_qkv<<<3328, 256, 0, stream>>>(comb16, wq16, wk16, wv16, bq, bk, bv,
                                  qf16, kf16, vt16, h, lab, sums, cnt, qscale);
  // 3) flash attention (split-K, L2-direct operands, XCD-pinned combos)
  k_attn_mfma<<<1024, 256, 0, stream>>>(qf16, kf16, vt16, pO, pM, pL);
  // 4) merge -> hp16 [4096][1024]  |  GRU->c2n (also writes out_uch)
  k_mergeplus<<<1056, 256, 0, stream>>>(pO, pM, pL, hp16, sums, cnt, ch,
                                        gWih, gbih, gWhh, gbhh, Wp, bp, out_uch, c2n);
  // 5) MLP1
  k_gemm16<1><<<dim3(64, 4), 256, 0, stream>>>(hp16, w116, b1, nullptr, nullptr, nullptr,
                                               y116, 4096, 1024, 256, 1.0f);
  // 6) MLP2 (cols 128..255) fused with +h resid and +c2n[lab] -> final output
  k_gemm16<3><<<dim3(64, 2), 256, 0, stream>>>(y116, w216 + 128 * 256, b2 + 128, h, lab, c2n,
                                               outp, 4096, 256, 128, 1.0f);
}

// Round 10
// 253.557 us; speedup vs baseline: 1.1094x; 1.1094x over previous
//
#include <hip/hip_runtime.h>
#include <math.h>

#define N_NODES 4096
#define NHEADS  4
#define NSPLIT  4
#define KVRANGE 1024   // 4096 / NSPLIT

typedef _Float16 f16;
typedef _Float16 half8 __attribute__((ext_vector_type(8)));
typedef float f32x4 __attribute__((ext_vector_type(4)));

// ---------------------------------------------------------------- GEMM body (f16 in, f32 acc)
// out[m][j] = sum_k A[m][k] * B[j][k] (+ bias) ; A [M][K], B [J][K] f16, K % 64 == 0
// Register-prefetch staging: next tile's global loads issue before MFMA (latency hidden).
// EPI: 0 f16 out, col-bias, *alpha   1 f16 out, col-bias, relu
//      2 f16 out, row-bias           3 f32 out, col-bias, + resid + c2n[lab[m]]
template <int EPI>
__device__ __forceinline__ void gemm_body(const f16* __restrict__ A,
                                          const f16* __restrict__ B,
                                          const float* __restrict__ bias,
                                          const float* __restrict__ resid,
                                          const int* __restrict__ lab,
                                          const float* __restrict__ c2n,
                                          void* __restrict__ outv,
                                          int M, int K, int J, float alpha,
                                          int bx, int by, f16* smem) {
  f16* As = smem;             // 64 rows x 128B, XOR-swizzled chunks
  f16* Bs = smem + 64 * 64;
  const int t  = threadIdx.x;
  const int mb = bx * 64, jb = by * 64;
  const int w  = t >> 6, l = t & 63;
  const int g_ = l >> 4, c_ = l & 15;
  const int m0 = (w >> 1) * 32, n0 = (w & 1) * 32;
  const int r0 = t >> 3, ch0 = t & 7;          // staging coords (rows r0, r0+32)

  f32x4 acc[2][2];
#pragma unroll
  for (int i = 0; i < 2; ++i)
#pragma unroll
    for (int j = 0; j < 2; ++j) acc[i][j] = (f32x4){0.f, 0.f, 0.f, 0.f};

  // prologue: tile 0 -> regs
  uint4 ra0 = *(const uint4*)&A[(size_t)(mb + r0) * K + ch0 * 8];
  uint4 ra1 = *(const uint4*)&A[(size_t)(mb + r0 + 32) * K + ch0 * 8];
  uint4 rb0 = *(const uint4*)&B[(size_t)(jb + r0) * K + ch0 * 8];
  uint4 rb1 = *(const uint4*)&B[(size_t)(jb + r0 + 32) * K + ch0 * 8];
  const int sw = (ch0 ^ (r0 & 7)) << 3;        // (r0+32)&7 == r0&7

#define FRAG16(BUF, row, kh) \
  (*(const half8*)&BUF[(size_t)(row) * 64 + (((((kh) * 4 + g_) ^ (c_ & 7))) << 3)])

  for (int kb = 0; kb < K; kb += 64) {
    __syncthreads();                 // previous MFMA reads done
    *(uint4*)&As[r0 * 64 + sw]        = ra0;
    *(uint4*)&As[(r0 + 32) * 64 + sw] = ra1;
    *(uint4*)&Bs[r0 * 64 + sw]        = rb0;
    *(uint4*)&Bs[(r0 + 32) * 64 + sw] = rb1;
    __syncthreads();                 // tile ready
    if (kb + 64 < K) {               // issue next-tile loads; latency hides under MFMA
      ra0 = *(const uint4*)&A[(size_t)(mb + r0) * K + kb + 64 + ch0 * 8];
      ra1 = *(const uint4*)&A[(size_t)(mb + r0 + 32) * K + kb + 64 + ch0 * 8];
      rb0 = *(const uint4*)&B[(size_t)(jb + r0) * K + kb + 64 + ch0 * 8];
      rb1 = *(const uint4*)&B[(size_t)(jb + r0 + 32) * K + kb + 64 + ch0 * 8];
    }
#pragma unroll
    for (int kh = 0; kh < 2; ++kh) {
      half8 a0 = FRAG16(As, m0 + c_, kh);
      half8 a1 = FRAG16(As, m0 + 16 + c_, kh);
      half8 b0 = FRAG16(Bs, n0 + c_, kh);
      half8 b1 = FRAG16(Bs, n0 + 16 + c_, kh);
      acc[0][0] = __builtin_amdgcn_mfma_f32_16x16x32_f16(a0, b0, acc[0][0], 0, 0, 0);
      acc[0][1] = __builtin_amdgcn_mfma_f32_16x16x32_f16(a0, b1, acc[0][1], 0, 0, 0);
      acc[1][0] = __builtin_amdgcn_mfma_f32_16x16x32_f16(a1, b0, acc[1][0], 0, 0, 0);
      acc[1][1] = __builtin_amdgcn_mfma_f32_16x16x32_f16(a1, b1, acc[1][1], 0, 0, 0);
    }
  }
#undef FRAG16

#pragma unroll
  for (int mt = 0; mt < 2; ++mt)
#pragma unroll
    for (int nt = 0; nt < 2; ++nt) {
      int mbase = mb + m0 + mt * 16 + g_ * 4;
      int jj    = jb + n0 + nt * 16 + c_;
      if (EPI == 0 || EPI == 1) {
        f16* out = (f16*)outv;
        float bc = bias[jj];
#pragma unroll
        for (int r = 0; r < 4; ++r) {
          float v = (acc[mt][nt][r] + bc) * alpha;
          if (EPI == 1) v = fmaxf(v, 0.f);
          out[(size_t)(mbase + r) * J + jj] = (f16)v;
        }
      } else if (EPI == 2) {
        f16* out = (f16*)outv;
#pragma unroll
        for (int r = 0; r < 4; ++r)
          out[(size_t)(mbase + r) * J + jj] = (f16)(acc[mt][nt][r] + bias[mbase + r]);
      } else {
        float* out = (float*)outv;
        float bc = bias[jj];
#pragma unroll
        for (int r = 0; r < 4; ++r) {
          int m = mbase + r;
          out[(size_t)m * J + jj] = acc[mt][nt][r] + bc +
              resid[(size_t)m * J + jj] + c2n[lab[m] * 128 + jj];
        }
      }
    }
}

template <int EPI>
__global__ __launch_bounds__(256) void k_gemm16(const f16* __restrict__ A,
                                                const f16* __restrict__ B,
                                                const float* __restrict__ bias,
                                                const float* __restrict__ resid,
                                                const int* __restrict__ lab,
                                                const float* __restrict__ c2n,
                                                void* __restrict__ outv,
                                                int M, int K, int J, float alpha) {
  __shared__ f16 smem[2 * 64 * 64];
  gemm_body<EPI>(A, B, bias, resid, lab, c2n, outv, M, K, J, alpha,
                 blockIdx.x, blockIdx.y, smem);
}

// ---------------------------------------------------------------- prep: combined + w2h + zero
// pool: [Wq 32768][Wk 32768][Wv 262144][W1 262144][W2 65536] = 655360
__global__ __launch_bounds__(256) void k_prep(const float* __restrict__ x,
                                              const float* __restrict__ h,
                                              const float* __restrict__ Wq,
                                              const float* __restrict__ Wk,
                                              const float* __restrict__ Wv,
                                              const float* __restrict__ W1,
                                              const float* __restrict__ W2,
                                              f16* __restrict__ comb16,
                                              f16* __restrict__ pool,
                                              float* __restrict__ sums) {
  const int b = blockIdx.x, t = threadIdx.x;
  if (b < 1024) {                      // combined = [x, h] -> f16
    int i = b * 256 + t;               // over N*64 float4
    int n = i >> 6, c = i & 63;
    float4 v;
    if (c < 32) v = ((const float4*)x)[n * 32 + c];
    else        v = ((const float4*)h)[n * 32 + (c - 32)];
    union { uint2 u; f16 h4[4]; } pk;
    pk.h4[0] = (f16)v.x; pk.h4[1] = (f16)v.y; pk.h4[2] = (f16)v.z; pk.h4[3] = (f16)v.w;
    *(uint2*)&comb16[(size_t)i * 4] = pk.u;
  } else if (b < 1664) {               // weights -> f16
    int i4 = ((b - 1024) * 256 + t) * 4;
    const float* src; int off;
    if      (i4 <  32768) { src = Wq; off = 0; }
    else if (i4 <  65536) { src = Wk; off = 32768; }
    else if (i4 < 327680) { src = Wv; off = 65536; }
    else if (i4 < 589824) { src = W1; off = 327680; }
    else                  { src = W2; off = 589824; }
    float4 v = *(const float4*)&src[i4 - off];
    union { uint2 u; f16 h4[4]; } pk;
    pk.h4[0] = (f16)v.x; pk.h4[1] = (f16)v.y; pk.h4[2] = (f16)v.z; pk.h4[3] = (f16)v.w;
    *(uint2*)&pool[i4] = pk.u;
  } else {                             // zero sums[8192] + cnt[64] (contiguous)
    int i = (b - 1664) * 256 + t;
    if (i < 8256) sums[i] = 0.f;
  }
}

// ---------------------------------------------------------------- qkv: V-proj | Q-proj | K-proj | segsum
__global__ __launch_bounds__(256) void k_qkv(const f16* __restrict__ comb16,
                                             const f16* __restrict__ wq16,
                                             const f16* __restrict__ wk16,
                                             const f16* __restrict__ wv16,
                                             const float* __restrict__ bq,
                                             const float* __restrict__ bk,
                                             const float* __restrict__ bv,
                                             f16* __restrict__ qf16,
                                             f16* __restrict__ kf16,
                                             f16* __restrict__ vt16,
                                             const float* __restrict__ h,
                                             const int* __restrict__ lab,
                                             float* __restrict__ sums,
                                             float* __restrict__ cnt,
                                             float qscale) {
  __shared__ f16 smem[2 * 64 * 64];
  const int b = blockIdx.x;
  if (b < 1024) {            // V^T: A = Wv [1024][256], B = comb -> vt [1024][4096]
    gemm_body<2>(wv16, comb16, bv, nullptr, nullptr, nullptr, vt16,
                 1024, 256, 4096, 1.0f, b & 15, b >> 4, smem);
  } else if (b < 1152) {     // Q (pre-scaled)
    int r = b - 1024;
    gemm_body<0>(comb16, wq16, bq, nullptr, nullptr, nullptr, qf16,
                 4096, 256, 128, qscale, r & 63, r >> 6, smem);
  } else if (b < 1280) {     // K
    int r = b - 1152;
    gemm_body<0>(comb16, wk16, bk, nullptr, nullptr, nullptr, kf16,
                 4096, 256, 128, 1.0f, r & 63, r >> 6, smem);
  } else {                   // segment sum over h
    int i = (b - 1280) * 256 + threadIdx.x;   // N*128
    int n = i >> 7, d = i & 127;
    int c = lab[n];
    atomicAdd(&sums[c * 128 + d], h[i]);
    if (d == 0) atomicAdd(&cnt[c], 1.0f);
  }
}

// ---------------------------------------------------------------- MFMA flash attention (+GRU blocks)
// Attention blocks (bx<64): round-7 LDS-staged d-split kernel.
// bx>=64: GRU+c2n blocks (independent of attention; run concurrently in this dispatch).
__global__ __launch_bounds__(256, 3) void k_attn_mfma(const f16* __restrict__ qg,
                                                      const f16* __restrict__ kg,
                                                      const f16* __restrict__ vt,
                                                      f16* __restrict__ pO,
                                                      float* __restrict__ pM,
                                                      float* __restrict__ pL,
                                                      const float* __restrict__ sums,
                                                      const float* __restrict__ cnt,
                                                      const float* __restrict__ ch,
                                                      const float* __restrict__ gWih,
                                                      const float* __restrict__ gbih,
                                                      const float* __restrict__ gWhh,
                                                      const float* __restrict__ gbhh,
                                                      const float* __restrict__ Wp,
                                                      const float* __restrict__ bp,
                                                      float* __restrict__ out_uch,
                                                      float* __restrict__ c2n) {
  __shared__ f16 Ks[32 * 40];          // [kv][e] pad 40
  __shared__ f16 Vs[256 * 40];         // [d][kv] pad 40
  __shared__ f16 Ps[64 * 40];          // [q][kv] pad 40 (B-frag layout)
  __shared__ float CfS[64];            // per-q rescale factor (then final l)

  const int hd  = blockIdx.y;
  const int sp  = blockIdx.z;
  const int t   = threadIdx.x;

  if (blockIdx.x >= 64) {              // ---- GRU + c2n path (32 blocks total)
    const int gid = (blockIdx.x - 64) * 16 + hd * 4 + sp;   // 0..31
    float* ax = (float*)Vs;            // alias LDS: 2x128 floats each
    float* hx = ax + 256;
    float* ul = hx + 256;
    const int cc = t >> 7, d = t & 127;
    const int c  = gid * 2 + cc;
    float count = cnt[c];
    ax[cc * 128 + d] = sums[c * 128 + d] / fmaxf(count, 1.0f);
    hx[cc * 128 + d] = ch[c * 128 + d];
    __syncthreads();
    float gi[3], gh[3];
#pragma unroll
    for (int g = 0; g < 3; ++g) {
      const float4* wi4 = (const float4*)&gWih[(size_t)(g * 128 + d) * 128];
      const float4* wh4 = (const float4*)&gWhh[(size_t)(g * 128 + d) * 128];
      float si = 0.f, sh = 0.f;
#pragma unroll 8
      for (int e = 0; e < 32; ++e) {
        float4 wv = wi4[e], hv = wh4[e];
        si = fmaf(ax[cc*128+e*4+0], wv.x, si); si = fmaf(ax[cc*128+e*4+1], wv.y, si);
        si = fmaf(ax[cc*128+e*4+2], wv.z, si); si = fmaf(ax[cc*128+e*4+3], wv.w, si);
        sh = fmaf(hx[cc*128+e*4+0], hv.x, sh); sh = fmaf(hx[cc*128+e*4+1], hv.y, sh);
        sh = fmaf(hx[cc*128+e*4+2], hv.z, sh); sh = fmaf(hx[cc*128+e*4+3], hv.w, sh);
      }
      gi[g] = si + gbih[g * 128 + d];
      gh[g] = sh + gbhh[g * 128 + d];
    }
    float r = 1.f / (1.f + expf(-(gi[0] + gh[0])));
    float z = 1.f / (1.f + expf(-(gi[1] + gh[1])));
    float nn = tanhf(gi[2] + r * gh[2]);
    float hv = hx[cc * 128 + d];
    float nh = (1.f - z) * nn + z * hv;
    float res = (count > 0.f) ? nh : hv;
    ul[cc * 128 + d] = res;
    out_uch[c * 128 + d] = res;
    __syncthreads();
    const float4* w4 = (const float4*)&Wp[(size_t)d * 128];
    float s = 0.f;
#pragma unroll 8
    for (int e = 0; e < 32; ++e) {
      float4 wv = w4[e];
      s = fmaf(ul[cc*128+e*4+0], wv.x, s); s = fmaf(ul[cc*128+e*4+1], wv.y, s);
      s = fmaf(ul[cc*128+e*4+2], wv.z, s); s = fmaf(ul[cc*128+e*4+3], wv.w, s);
    }
    c2n[c * 128 + d] = s + bp[d];
    return;
  }

  // ---- attention path (round-7 kernel)
  const int kv0 = sp * KVRANGE;
  const int w   = t >> 6, l = t & 63;
  const int g   = l >> 4, c = l & 15;
  const int qb  = blockIdx.x * 64;     // block owns 64 q

  // Q fragment for this wave's q-group (q = qb + w*16 + c)
  half8 qf = *(const half8*)&qg[(size_t)(qb + w * 16 + c) * 128 + hd * 32 + g * 8];

  f32x4 oacc[4][4];                    // [dt_local][qt]; d = (w*4+i)*16+g*4+r, q = qb+qt*16+c
#pragma unroll
  for (int i = 0; i < 4; ++i)
#pragma unroll
    for (int j = 0; j < 4; ++j) oacc[i][j] = (f32x4){0.f, 0.f, 0.f, 0.f};
  float m_run = -INFINITY, l_run = 0.f;
  const f32x4 zero4 = {0.f, 0.f, 0.f, 0.f};

  for (int kb = 0; kb < KVRANGE; kb += 32) {
    __syncthreads();   // prev PV / CfS reads complete before tiles are overwritten
    if (t < 128) {     // K tile: 32 x 32 f16 = 128 uint4
      int r = t >> 2, c8 = (t & 3) * 8;
      *(uint4*)&Ks[r * 40 + c8] =
          *(const uint4*)&kg[(size_t)(kv0 + kb + r) * 128 + hd * 32 + c8];
    }
#pragma unroll
    for (int i = 0; i < 4; ++i) {      // V^T tile: 256 x 32 f16 = 1024 uint4
      int cc = i * 256 + t, d = cc >> 2, c8 = (cc & 3) * 8;
      *(uint4*)&Vs[d * 40 + c8] =
          *(const uint4*)&vt[(size_t)(hd * 256 + d) * 4096 + kv0 + kb + c8];
    }
    __syncthreads();   // tiles ready

    // ---- QK^T for this wave's 16 q (swapped: S^T tile, lane reg r -> kv = g*4+r / +16)
    f32x4 s0 = __builtin_amdgcn_mfma_f32_16x16x32_f16(
        *(const half8*)&Ks[(c) * 40 + g * 8], qf, zero4, 0, 0, 0);
    f32x4 s1 = __builtin_amdgcn_mfma_f32_16x16x32_f16(
        *(const half8*)&Ks[(16 + c) * 40 + g * 8], qf, zero4, 0, 0, 0);

    float sv[8];
#pragma unroll
    for (int r = 0; r < 4; ++r) {
      float a = s0[r]; sv[r]     = a > 0.f ? a : 0.2f * a;   // leaky(0.2), scale in q
      float b = s1[r]; sv[4 + r] = b > 0.f ? b : 0.2f * b;
    }
    float mx = sv[0];
#pragma unroll
    for (int r = 1; r < 8; ++r) mx = fmaxf(mx, sv[r]);
    mx = fmaxf(mx, __shfl_xor(mx, 16));
    mx = fmaxf(mx, __shfl_xor(mx, 32));

    float cf = 1.f;
    if (!__all(mx <= m_run + 8.f)) {   // defer-max
      float m_new = fmaxf(m_run, mx);
      cf = __expf(m_run - m_new);
      m_run = m_new;
    }
    float p[8], ps = 0.f;
#pragma unroll
    for (int r = 0; r < 8; ++r) { p[r] = __expf(sv[r] - m_run); ps += p[r]; }
    ps += __shfl_xor(ps, 16);
    ps += __shfl_xor(ps, 32);
    l_run = l_run * cf + ps;

    if (g == 0) CfS[w * 16 + c] = cf;
    // pack P -> Ps[q][kv] (pairs are kv-consecutive: reg r -> kv g*4+r, +16)
    {
      union { unsigned u; f16 h2[2]; } z;
      uint2 lo, hi;
      z.h2[0] = (f16)p[0]; z.h2[1] = (f16)p[1]; lo.x = z.u;
      z.h2[0] = (f16)p[2]; z.h2[1] = (f16)p[3]; lo.y = z.u;
      z.h2[0] = (f16)p[4]; z.h2[1] = (f16)p[5]; hi.x = z.u;
      z.h2[0] = (f16)p[6]; z.h2[1] = (f16)p[7]; hi.y = z.u;
      *(uint2*)&Ps[(w * 16 + c) * 40 + g * 4]      = lo;
      *(uint2*)&Ps[(w * 16 + c) * 40 + 16 + g * 4] = hi;
    }
    __syncthreads();   // P + Cf ready

    // ---- rescale accumulators by per-q cf
#pragma unroll
    for (int qt = 0; qt < 4; ++qt) {
      float cfq = CfS[qt * 16 + c];
      if (!__all(cfq == 1.f)) {
#pragma unroll
        for (int i = 0; i < 4; ++i) {
          oacc[i][qt][0] *= cfq; oacc[i][qt][1] *= cfq;
          oacc[i][qt][2] *= cfq; oacc[i][qt][3] *= cfq;
        }
      }
    }
    // ---- PV: this wave's d-slice (dt = w*4+i), all 4 q-tiles
    half8 pfr[4];
#pragma unroll
    for (int qt = 0; qt < 4; ++qt)
      pfr[qt] = *(const half8*)&Ps[(qt * 16 + c) * 40 + g * 8];
#pragma unroll
    for (int i = 0; i < 4; ++i) {
      half8 vfr = *(const half8*)&Vs[((w * 4 + i) * 16 + c) * 40 + g * 8];
#pragma unroll
      for (int qt = 0; qt < 4; ++qt)
        oacc[i][qt] = __builtin_amdgcn_mfma_f32_16x16x32_f16(vfr, pfr[qt], oacc[i][qt], 0, 0, 0);
    }
  }

  // broadcast final l per q, then write normalized partials
  __syncthreads();
  if (g == 0) CfS[w * 16 + c] = l_run;
  __syncthreads();
  float linv[4];
#pragma unroll
  for (int qt = 0; qt < 4; ++qt) linv[qt] = 1.f / CfS[qt * 16 + c];
#pragma unroll
  for (int i = 0; i < 4; ++i)
#pragma unroll
    for (int qt = 0; qt < 4; ++qt)
#pragma unroll
      for (int r = 0; r < 4; ++r) {
        int j = hd * 256 + (w * 4 + i) * 16 + g * 4 + r;
        pO[(size_t)(sp * 1024 + j) * 4096 + qb + qt * 16 + c] =
            (f16)(oacc[i][qt][r] * linv[qt]);
      }
  if (g == 0) {
    pM[(sp * 4 + hd) * 4096 + qb + w * 16 + c] = m_run;
    pL[(sp * 4 + hd) * 4096 + qb + w * 16 + c] = l_run;
  }
}

// ---------------------------------------------------------------- split-K merge -> hp16 [4096][1024]
__global__ __launch_bounds__(256) void k_merge(const f16* __restrict__ pO,
                                               const float* __restrict__ pM,
                                               const float* __restrict__ pL,
                                               f16* __restrict__ hp) {
  const int b = blockIdx.x, t = threadIdx.x;
  __shared__ float wm[NSPLIT][64], wl[NSPLIT][64];
  __shared__ float tile[64][65];
  const int q0 = (b & 63) * 64, jb = (b >> 6) * 64;
  const int h  = jb >> 8;

  if (t < 64) {
#pragma unroll
    for (int s = 0; s < NSPLIT; ++s) {
      wm[s][t] = pM[(s * 4 + h) * 4096 + q0 + t];
      wl[s][t] = pL[(s * 4 + h) * 4096 + q0 + t];
    }
  }
  __syncthreads();

  const int q8 = (t & 7) * 8;
#pragma unroll
  for (int it = 0; it < 2; ++it) {
    int jl = (t >> 3) + it * 32;
    float wgt[NSPLIT][8], inv[8];
#pragma unroll
    for (int q = 0; q < 8; ++q) {
      float M = wm[0][q8 + q];
#pragma unroll
      for (int s = 1; s < NSPLIT; ++s) M = fmaxf(M, wm[s][q8 + q]);
      float den = 0.f;
#pragma unroll
      for (int s = 0; s < NSPLIT; ++s) {
        float wv = wl[s][q8 + q] * __expf(wm[s][q8 + q] - M);
        wgt[s][q] = wv; den += wv;
      }
      inv[q] = 1.f / den;
    }
    float o[8] = {0.f};
#pragma unroll
    for (int s = 0; s < NSPLIT; ++s) {
      union { uint4 u; f16 h8[8]; } raw;
      raw.u = *(const uint4*)&pO[(size_t)(s * 1024 + jb + jl) * 4096 + q0 + q8];
#pragma unroll
      for (int q = 0; q < 8; ++q) o[q] += wgt[s][q] * (float)raw.h8[q];
    }
#pragma unroll
    for (int q = 0; q < 8; ++q) tile[q8 + q][jl] = o[q] * inv[q];
  }
  __syncthreads();

#pragma unroll
  for (int it = 0; it < 2; ++it) {
    int ql = (t >> 3) + it * 32, chk = t & 7;
    union { uint4 u; f16 h8[8]; } pk;
#pragma unroll
    for (int k = 0; k < 8; ++k) pk.h8[k] = (f16)tile[ql][chk * 8 + k];
    *(uint4*)&hp[(size_t)(q0 + ql) * 1024 + jb + chk * 8] = pk.u;
  }
}

// ---------------------------------------------------------------- launch
extern "C" void kernel_launch(void* const* d_in, const int* in_sizes, int n_in,
                              void* d_out, int out_size, void* d_ws, size_t ws_size,
                              hipStream_t stream) {
  const float* x    = (const float*)d_in[0];
  const float* h    = (const float*)d_in[1];
  const float* ch   = (const float*)d_in[2];
  const int*   lab  = (const int*)d_in[4];
  const float* Wq   = (const float*)d_in[8];
  const float* bq   = (const float*)d_in[9];
  const float* Wk   = (const float*)d_in[10];
  const float* bk   = (const float*)d_in[11];
  const float* Wv   = (const float*)d_in[12];
  const float* bv   = (const float*)d_in[13];
  const float* W1   = (const float*)d_in[14];
  const float* b1   = (const float*)d_in[15];
  const float* W2   = (const float*)d_in[16];
  const float* b2   = (const float*)d_in[17];
  const float* gWih = (const float*)d_in[18];
  const float* gbih = (const float*)d_in[19];
  const float* gWhh = (const float*)d_in[20];
  const float* gbhh = (const float*)d_in[21];
  const float* Wp   = (const float*)d_in[22];
  const float* bp   = (const float*)d_in[23];

  float* outp    = (float*)d_out;                 // [4096*128] updated_h
  float* out_uch = outp + 4096 * 128;             // [64*128] updated_cluster_h

  // ---- workspace layout
  f16* comb16 = (f16*)d_ws;                        // 4096*256
  f16* w16    = comb16 + 4096 * 256;               // 655360
  f16* wq16   = w16;                               //  32768
  f16* wk16   = w16 + 32768;
  f16* wv16   = w16 + 65536;                       // 262144 [1024][256]
  f16* w116   = w16 + 327680;                      // 262144 [256][1024]
  f16* w216   = w16 + 589824;                      //  65536 [256][256]
  f16* qf16   = w16 + 655360;                      // 4096*128
  f16* kf16   = qf16 + 4096 * 128;                 // 4096*128
  f16* vt16   = kf16 + 4096 * 128;                 // 1024*4096
  f16* pO     = vt16 + 1024 * 4096;                // 4*1024*4096
  f16* hp16   = pO + (size_t)NSPLIT * 1024 * 4096; // 4096*1024
  f16* y116   = hp16 + (size_t)4096 * 1024;        // 4096*256
  float* pM   = (float*)(y116 + 4096 * 256);       // 4*4*4096
  float* pL   = pM + NSPLIT * 4 * 4096;
  float* sums = pL + NSPLIT * 4 * 4096;            // 8192 (+64 cnt contiguous)
  float* cnt  = sums + 64 * 128;                   // 64
  float* c2n  = cnt + 64;                          // 8192

  const float qscale = 0.17677669529663687f;       // 1/sqrt(32)

  // 1) combined(f16) + weights->f16 + zero(sums,cnt)
  k_prep<<<1697, 256, 0, stream>>>(x, h, Wq, Wk, Wv, W1, W2, comb16, w16, sums);
  // 2) V^T | Q | K projections + segsum, all concurrent
  k_qkv<<<3328, 256, 0, stream>>>(comb16, wq16, wk16, wv16, bq, bk, bv,
                                  qf16, kf16, vt16, h, lab, sums, cnt, qscale);
  // 3) flash attention (split-K, LDS-staged) with concurrent GRU->c2n blocks
  k_attn_mfma<<<dim3(66, NHEADS, NSPLIT), 256, 0, stream>>>(
      qf16, kf16, vt16, pO, pM, pL,
      sums, cnt, ch, gWih, gbih, gWhh, gbhh, Wp, bp, out_uch, c2n);
  // 4) merge -> hp16 [4096][1024]
  k_merge<<<1024, 256, 0, stream>>>(pO, pM, pL, hp16);
  // 5) MLP1
  k_gemm16<1><<<dim3(64, 4), 256, 0, stream>>>(hp16, w116, b1, nullptr, nullptr, nullptr,
                                               y116, 4096, 1024, 256, 1.0f);
  // 6) MLP2 (cols 128..255) fused with +h resid and +c2n[lab] -> final output
  k_gemm16<3><<<dim3(64, 2), 256, 0, stream>>>(y116, w216 + 128 * 256, b2 + 128, h, lab, c2n,
                                               outp, 4096, 256, 128, 1.0f);
}

// Round 11
// 253.504 us; speedup vs baseline: 1.1096x; 1.0002x over previous
//
#include <hip/hip_runtime.h>
#include <math.h>

#define N_NODES 4096
#define NHEADS  4
#define NSPLIT  4
#define KVRANGE 1024   // 4096 / NSPLIT

typedef _Float16 f16;
typedef _Float16 half8 __attribute__((ext_vector_type(8)));
typedef float f32x4 __attribute__((ext_vector_type(4)));

// ---------------------------------------------------------------- GEMM body (f16 in, f32 acc)
// out[m][j] = sum_k A[m][k] * B[j][k] (+ bias) ; A [M][K], B [J][K] f16, K % 64 == 0
// Register-prefetch staging: next tile's global loads issue before MFMA (latency hidden).
// EPI: 0 f16 out, col-bias, *alpha   1 f16 out, col-bias, relu
//      2 f16 out, row-bias           3 f32 out, col-bias, + resid + c2n[lab[m]]
template <int EPI>
__device__ __forceinline__ void gemm_body(const f16* __restrict__ A,
                                          const f16* __restrict__ B,
                                          const float* __restrict__ bias,
                                          const float* __restrict__ resid,
                                          const int* __restrict__ lab,
                                          const float* __restrict__ c2n,
                                          void* __restrict__ outv,
                                          int M, int K, int J, float alpha,
                                          int bx, int by, f16* smem) {
  f16* As = smem;             // 64 rows x 128B, XOR-swizzled chunks
  f16* Bs = smem + 64 * 64;
  const int t  = threadIdx.x;
  const int mb = bx * 64, jb = by * 64;
  const int w  = t >> 6, l = t & 63;
  const int g_ = l >> 4, c_ = l & 15;
  const int m0 = (w >> 1) * 32, n0 = (w & 1) * 32;
  const int r0 = t >> 3, ch0 = t & 7;          // staging coords (rows r0, r0+32)

  f32x4 acc[2][2];
#pragma unroll
  for (int i = 0; i < 2; ++i)
#pragma unroll
    for (int j = 0; j < 2; ++j) acc[i][j] = (f32x4){0.f, 0.f, 0.f, 0.f};

  // prologue: tile 0 -> regs
  uint4 ra0 = *(const uint4*)&A[(size_t)(mb + r0) * K + ch0 * 8];
  uint4 ra1 = *(const uint4*)&A[(size_t)(mb + r0 + 32) * K + ch0 * 8];
  uint4 rb0 = *(const uint4*)&B[(size_t)(jb + r0) * K + ch0 * 8];
  uint4 rb1 = *(const uint4*)&B[(size_t)(jb + r0 + 32) * K + ch0 * 8];
  const int sw = (ch0 ^ (r0 & 7)) << 3;        // (r0+32)&7 == r0&7

#define FRAG16(BUF, row, kh) \
  (*(const half8*)&BUF[(size_t)(row) * 64 + (((((kh) * 4 + g_) ^ (c_ & 7))) << 3)])

  for (int kb = 0; kb < K; kb += 64) {
    __syncthreads();                 // previous MFMA reads done
    *(uint4*)&As[r0 * 64 + sw]        = ra0;
    *(uint4*)&As[(r0 + 32) * 64 + sw] = ra1;
    *(uint4*)&Bs[r0 * 64 + sw]        = rb0;
    *(uint4*)&Bs[(r0 + 32) * 64 + sw] = rb1;
    __syncthreads();                 // tile ready
    if (kb + 64 < K) {               // issue next-tile loads; latency hides under MFMA
      ra0 = *(const uint4*)&A[(size_t)(mb + r0) * K + kb + 64 + ch0 * 8];
      ra1 = *(const uint4*)&A[(size_t)(mb + r0 + 32) * K + kb + 64 + ch0 * 8];
      rb0 = *(const uint4*)&B[(size_t)(jb + r0) * K + kb + 64 + ch0 * 8];
      rb1 = *(const uint4*)&B[(size_t)(jb + r0 + 32) * K + kb + 64 + ch0 * 8];
    }
#pragma unroll
    for (int kh = 0; kh < 2; ++kh) {
      half8 a0 = FRAG16(As, m0 + c_, kh);
      half8 a1 = FRAG16(As, m0 + 16 + c_, kh);
      half8 b0 = FRAG16(Bs, n0 + c_, kh);
      half8 b1 = FRAG16(Bs, n0 + 16 + c_, kh);
      acc[0][0] = __builtin_amdgcn_mfma_f32_16x16x32_f16(a0, b0, acc[0][0], 0, 0, 0);
      acc[0][1] = __builtin_amdgcn_mfma_f32_16x16x32_f16(a0, b1, acc[0][1], 0, 0, 0);
      acc[1][0] = __builtin_amdgcn_mfma_f32_16x16x32_f16(a1, b0, acc[1][0], 0, 0, 0);
      acc[1][1] = __builtin_amdgcn_mfma_f32_16x16x32_f16(a1, b1, acc[1][1], 0, 0, 0);
    }
  }
#undef FRAG16

#pragma unroll
  for (int mt = 0; mt < 2; ++mt)
#pragma unroll
    for (int nt = 0; nt < 2; ++nt) {
      int mbase = mb + m0 + mt * 16 + g_ * 4;
      int jj    = jb + n0 + nt * 16 + c_;
      if (EPI == 0 || EPI == 1) {
        f16* out = (f16*)outv;
        float bc = bias[jj];
#pragma unroll
        for (int r = 0; r < 4; ++r) {
          float v = (acc[mt][nt][r] + bc) * alpha;
          if (EPI == 1) v = fmaxf(v, 0.f);
          out[(size_t)(mbase + r) * J + jj] = (f16)v;
        }
      } else if (EPI == 2) {
        f16* out = (f16*)outv;
#pragma unroll
        for (int r = 0; r < 4; ++r)
          out[(size_t)(mbase + r) * J + jj] = (f16)(acc[mt][nt][r] + bias[mbase + r]);
      } else {
        float* out = (float*)outv;
        float bc = bias[jj];
#pragma unroll
        for (int r = 0; r < 4; ++r) {
          int m = mbase + r;
          out[(size_t)m * J + jj] = acc[mt][nt][r] + bc +
              resid[(size_t)m * J + jj] + c2n[lab[m] * 128 + jj];
        }
      }
    }
}

template <int EPI>
__global__ __launch_bounds__(256) void k_gemm16(const f16* __restrict__ A,
                                                const f16* __restrict__ B,
                                                const float* __restrict__ bias,
                                                const float* __restrict__ resid,
                                                const int* __restrict__ lab,
                                                const float* __restrict__ c2n,
                                                void* __restrict__ outv,
                                                int M, int K, int J, float alpha) {
  __shared__ f16 smem[2 * 64 * 64];
  gemm_body<EPI>(A, B, bias, resid, lab, c2n, outv, M, K, J, alpha,
                 blockIdx.x, blockIdx.y, smem);
}

// ---------------------------------------------------------------- prep: combined + w2h + zero
// pool: [Wq 32768][Wk 32768][Wv 262144][W1 262144][W2 65536] = 655360
__global__ __launch_bounds__(256) void k_prep(const float* __restrict__ x,
                                              const float* __restrict__ h,
                                              const float* __restrict__ Wq,
                                              const float* __restrict__ Wk,
                                              const float* __restrict__ Wv,
                                              const float* __restrict__ W1,
                                              const float* __restrict__ W2,
                                              f16* __restrict__ comb16,
                                              f16* __restrict__ pool,
                                              float* __restrict__ sums) {
  const int b = blockIdx.x, t = threadIdx.x;
  if (b < 1024) {                      // combined = [x, h] -> f16
    int i = b * 256 + t;               // over N*64 float4
    int n = i >> 6, c = i & 63;
    float4 v;
    if (c < 32) v = ((const float4*)x)[n * 32 + c];
    else        v = ((const float4*)h)[n * 32 + (c - 32)];
    union { uint2 u; f16 h4[4]; } pk;
    pk.h4[0] = (f16)v.x; pk.h4[1] = (f16)v.y; pk.h4[2] = (f16)v.z; pk.h4[3] = (f16)v.w;
    *(uint2*)&comb16[(size_t)i * 4] = pk.u;
  } else if (b < 1664) {               // weights -> f16
    int i4 = ((b - 1024) * 256 + t) * 4;
    const float* src; int off;
    if      (i4 <  32768) { src = Wq; off = 0; }
    else if (i4 <  65536) { src = Wk; off = 32768; }
    else if (i4 < 327680) { src = Wv; off = 65536; }
    else if (i4 < 589824) { src = W1; off = 327680; }
    else                  { src = W2; off = 589824; }
    float4 v = *(const float4*)&src[i4 - off];
    union { uint2 u; f16 h4[4]; } pk;
    pk.h4[0] = (f16)v.x; pk.h4[1] = (f16)v.y; pk.h4[2] = (f16)v.z; pk.h4[3] = (f16)v.w;
    *(uint2*)&pool[i4] = pk.u;
  } else {                             // zero sums[8192] + cnt[64] (contiguous)
    int i = (b - 1664) * 256 + t;
    if (i < 8256) sums[i] = 0.f;
  }
}

// ---------------------------------------------------------------- qkv: V-proj | Q-proj | K-proj | segsum
__global__ __launch_bounds__(256) void k_qkv(const f16* __restrict__ comb16,
                                             const f16* __restrict__ wq16,
                                             const f16* __restrict__ wk16,
                                             const f16* __restrict__ wv16,
                                             const float* __restrict__ bq,
                                             const float* __restrict__ bk,
                                             const float* __restrict__ bv,
                                             f16* __restrict__ qf16,
                                             f16* __restrict__ kf16,
                                             f16* __restrict__ vt16,
                                             const float* __restrict__ h,
                                             const int* __restrict__ lab,
                                             float* __restrict__ sums,
                                             float* __restrict__ cnt,
                                             float qscale) {
  __shared__ f16 smem[2 * 64 * 64];
  const int b = blockIdx.x;
  if (b < 1024) {            // V^T: A = Wv [1024][256], B = comb -> vt [1024][4096]
    gemm_body<2>(wv16, comb16, bv, nullptr, nullptr, nullptr, vt16,
                 1024, 256, 4096, 1.0f, b & 15, b >> 4, smem);
  } else if (b < 1152) {     // Q (pre-scaled)
    int r = b - 1024;
    gemm_body<0>(comb16, wq16, bq, nullptr, nullptr, nullptr, qf16,
                 4096, 256, 128, qscale, r & 63, r >> 6, smem);
  } else if (b < 1280) {     // K
    int r = b - 1152;
    gemm_body<0>(comb16, wk16, bk, nullptr, nullptr, nullptr, kf16,
                 4096, 256, 128, 1.0f, r & 63, r >> 6, smem);
  } else {                   // segment sum over h
    int i = (b - 1280) * 256 + threadIdx.x;   // N*128
    int n = i >> 7, d = i & 127;
    int c = lab[n];
    atomicAdd(&sums[c * 128 + d], h[i]);
    if (d == 0) atomicAdd(&cnt[c], 1.0f);
  }
}

// ---------------------------------------------------------------- MFMA flash attention
// Round-7 LDS-staged d-split kernel + XCD-pinned 1-D block decode:
// each (head,split) combo's 64 q-blocks land on one XCD (block b -> XCD b%8),
// so the combo's K/V slices stay resident in that XCD's L2.
__global__ __launch_bounds__(256, 3) void k_attn_mfma(const f16* __restrict__ qg,
                                                      const f16* __restrict__ kg,
                                                      const f16* __restrict__ vt,
                                                      f16* __restrict__ pO,
                                                      float* __restrict__ pM,
                                                      float* __restrict__ pL) {
  const int b     = blockIdx.x;          // 0..1023
  const int xcd   = b & 7;
  const int i_    = b >> 3;              // 0..127
  const int combo = xcd * 2 + (i_ >> 6); // 0..15
  const int qblk  = i_ & 63;
  const int hd    = combo >> 2, sp = combo & 3;
  const int kv0   = sp * KVRANGE;
  const int qb    = qblk * 64;           // block owns 64 q

  const int t = threadIdx.x;
  const int w = t >> 6, l = t & 63;
  const int g = l >> 4, c = l & 15;

  __shared__ f16 Ks[32 * 40];          // [kv][e] pad 40
  __shared__ f16 Vs[256 * 40];         // [d][kv] pad 40
  __shared__ f16 Ps[64 * 40];          // [q][kv] pad 40 (B-frag layout)
  __shared__ float CfS[64];            // per-q rescale factor (then final l)

  // Q fragment for this wave's q-group (q = qb + w*16 + c)
  half8 qf = *(const half8*)&qg[(size_t)(qb + w * 16 + c) * 128 + hd * 32 + g * 8];

  f32x4 oacc[4][4];                    // [dt_local][qt]; d = (w*4+i)*16+g*4+r, q = qb+qt*16+c
#pragma unroll
  for (int i = 0; i < 4; ++i)
#pragma unroll
    for (int j = 0; j < 4; ++j) oacc[i][j] = (f32x4){0.f, 0.f, 0.f, 0.f};
  float m_run = -INFINITY, l_run = 0.f;
  const f32x4 zero4 = {0.f, 0.f, 0.f, 0.f};

  for (int kb = 0; kb < KVRANGE; kb += 32) {
    __syncthreads();   // prev PV / CfS reads complete before tiles are overwritten
    if (t < 128) {     // K tile: 32 x 32 f16 = 128 uint4
      int r = t >> 2, c8 = (t & 3) * 8;
      *(uint4*)&Ks[r * 40 + c8] =
          *(const uint4*)&kg[(size_t)(kv0 + kb + r) * 128 + hd * 32 + c8];
    }
#pragma unroll
    for (int i = 0; i < 4; ++i) {      // V^T tile: 256 x 32 f16 = 1024 uint4
      int cc = i * 256 + t, d = cc >> 2, c8 = (cc & 3) * 8;
      *(uint4*)&Vs[d * 40 + c8] =
          *(const uint4*)&vt[(size_t)(hd * 256 + d) * 4096 + kv0 + kb + c8];
    }
    __syncthreads();   // tiles ready

    // ---- QK^T for this wave's 16 q (swapped: S^T tile, lane reg r -> kv = g*4+r / +16)
    f32x4 s0 = __builtin_amdgcn_mfma_f32_16x16x32_f16(
        *(const half8*)&Ks[(c) * 40 + g * 8], qf, zero4, 0, 0, 0);
    f32x4 s1 = __builtin_amdgcn_mfma_f32_16x16x32_f16(
        *(const half8*)&Ks[(16 + c) * 40 + g * 8], qf, zero4, 0, 0, 0);

    float sv[8];
#pragma unroll
    for (int r = 0; r < 4; ++r) {
      float a = s0[r]; sv[r]     = a > 0.f ? a : 0.2f * a;   // leaky(0.2), scale in q
      float b2 = s1[r]; sv[4 + r] = b2 > 0.f ? b2 : 0.2f * b2;
    }
    float mx = sv[0];
#pragma unroll
    for (int r = 1; r < 8; ++r) mx = fmaxf(mx, sv[r]);
    mx = fmaxf(mx, __shfl_xor(mx, 16));
    mx = fmaxf(mx, __shfl_xor(mx, 32));

    float cf = 1.f;
    if (!__all(mx <= m_run + 8.f)) {   // defer-max
      float m_new = fmaxf(m_run, mx);
      cf = __expf(m_run - m_new);
      m_run = m_new;
    }
    float p[8], ps = 0.f;
#pragma unroll
    for (int r = 0; r < 8; ++r) { p[r] = __expf(sv[r] - m_run); ps += p[r]; }
    ps += __shfl_xor(ps, 16);
    ps += __shfl_xor(ps, 32);
    l_run = l_run * cf + ps;

    if (g == 0) CfS[w * 16 + c] = cf;
    // pack P -> Ps[q][kv] (pairs are kv-consecutive: reg r -> kv g*4+r, +16)
    {
      union { unsigned u; f16 h2[2]; } z;
      uint2 lo, hi;
      z.h2[0] = (f16)p[0]; z.h2[1] = (f16)p[1]; lo.x = z.u;
      z.h2[0] = (f16)p[2]; z.h2[1] = (f16)p[3]; lo.y = z.u;
      z.h2[0] = (f16)p[4]; z.h2[1] = (f16)p[5]; hi.x = z.u;
      z.h2[0] = (f16)p[6]; z.h2[1] = (f16)p[7]; hi.y = z.u;
      *(uint2*)&Ps[(w * 16 + c) * 40 + g * 4]      = lo;
      *(uint2*)&Ps[(w * 16 + c) * 40 + 16 + g * 4] = hi;
    }
    __syncthreads();   // P + Cf ready

    // ---- rescale accumulators by per-q cf
#pragma unroll
    for (int qt = 0; qt < 4; ++qt) {
      float cfq = CfS[qt * 16 + c];
      if (!__all(cfq == 1.f)) {
#pragma unroll
        for (int i = 0; i < 4; ++i) {
          oacc[i][qt][0] *= cfq; oacc[i][qt][1] *= cfq;
          oacc[i][qt][2] *= cfq; oacc[i][qt][3] *= cfq;
        }
      }
    }
    // ---- PV: this wave's d-slice (dt = w*4+i), all 4 q-tiles
    half8 pfr[4];
#pragma unroll
    for (int qt = 0; qt < 4; ++qt)
      pfr[qt] = *(const half8*)&Ps[(qt * 16 + c) * 40 + g * 8];
#pragma unroll
    for (int i = 0; i < 4; ++i) {
      half8 vfr = *(const half8*)&Vs[((w * 4 + i) * 16 + c) * 40 + g * 8];
#pragma unroll
      for (int qt = 0; qt < 4; ++qt)
        oacc[i][qt] = __builtin_amdgcn_mfma_f32_16x16x32_f16(vfr, pfr[qt], oacc[i][qt], 0, 0, 0);
    }
  }

  // broadcast final l per q, then write normalized partials
  __syncthreads();
  if (g == 0) CfS[w * 16 + c] = l_run;
  __syncthreads();
  float linv[4];
#pragma unroll
  for (int qt = 0; qt < 4; ++qt) linv[qt] = 1.f / CfS[qt * 16 + c];
#pragma unroll
  for (int i = 0; i < 4; ++i)
#pragma unroll
    for (int qt = 0; qt < 4; ++qt)
#pragma unroll
      for (int r = 0; r < 4; ++r) {
        int j = hd * 256 + (w * 4 + i) * 16 + g * 4 + r;
        pO[(size_t)(sp * 1024 + j) * 4096 + qb + qt * 16 + c] =
            (f16)(oacc[i][qt][r] * linv[qt]);
      }
  if (g == 0) {
    pM[(sp * 4 + hd) * 4096 + qb + w * 16 + c] = m_run;
    pL[(sp * 4 + hd) * 4096 + qb + w * 16 + c] = l_run;
  }
}

// ---------------------------------------------------------------- merge + fused GRU->c2n
__global__ __launch_bounds__(256) void k_mergeplus(const f16* __restrict__ pO,
                                                   const float* __restrict__ pM,
                                                   const float* __restrict__ pL,
                                                   f16* __restrict__ hp,
                                                   const float* __restrict__ sums,
                                                   const float* __restrict__ cnt,
                                                   const float* __restrict__ ch,
                                                   const float* __restrict__ gWih,
                                                   const float* __restrict__ gbih,
                                                   const float* __restrict__ gWhh,
                                                   const float* __restrict__ gbhh,
                                                   const float* __restrict__ Wp,
                                                   const float* __restrict__ bp,
                                                   float* __restrict__ out_uch,
                                                   float* __restrict__ c2n) {
  const int b = blockIdx.x, t = threadIdx.x;
  if (b < 1024) {                       // ---- split-K merge -> hp16 [4096][1024]
    __shared__ float wm[NSPLIT][64], wl[NSPLIT][64];
    __shared__ float tile[64][65];
    const int q0 = (b & 63) * 64, jb = (b >> 6) * 64;
    const int h  = jb >> 8;

    if (t < 64) {
#pragma unroll
      for (int s = 0; s < NSPLIT; ++s) {
        wm[s][t] = pM[(s * 4 + h) * 4096 + q0 + t];
        wl[s][t] = pL[(s * 4 + h) * 4096 + q0 + t];
      }
    }
    __syncthreads();

    const int q8 = (t & 7) * 8;
#pragma unroll
    for (int it = 0; it < 2; ++it) {
      int jl = (t >> 3) + it * 32;
      float wgt[NSPLIT][8], inv[8];
#pragma unroll
      for (int q = 0; q < 8; ++q) {
        float M = wm[0][q8 + q];
#pragma unroll
        for (int s = 1; s < NSPLIT; ++s) M = fmaxf(M, wm[s][q8 + q]);
        float den = 0.f;
#pragma unroll
        for (int s = 0; s < NSPLIT; ++s) {
          float wv = wl[s][q8 + q] * __expf(wm[s][q8 + q] - M);
          wgt[s][q] = wv; den += wv;
        }
        inv[q] = 1.f / den;
      }
      float o[8] = {0.f};
#pragma unroll
      for (int s = 0; s < NSPLIT; ++s) {
        union { uint4 u; f16 h8[8]; } raw;
        raw.u = *(const uint4*)&pO[(size_t)(s * 1024 + jb + jl) * 4096 + q0 + q8];
#pragma unroll
        for (int q = 0; q < 8; ++q) o[q] += wgt[s][q] * (float)raw.h8[q];
      }
#pragma unroll
      for (int q = 0; q < 8; ++q) tile[q8 + q][jl] = o[q] * inv[q];
    }
    __syncthreads();

#pragma unroll
    for (int it = 0; it < 2; ++it) {
      int ql = (t >> 3) + it * 32, chk = t & 7;
      union { uint4 u; f16 h8[8]; } pk;
#pragma unroll
      for (int k = 0; k < 8; ++k) pk.h8[k] = (f16)tile[ql][chk * 8 + k];
      *(uint4*)&hp[(size_t)(q0 + ql) * 1024 + jb + chk * 8] = pk.u;
    }
  } else {                              // ---- GRU + c2n, 2 clusters per block
    __shared__ float ax[2][128], hx[2][128], ul[2][128];
    const int cc = t >> 7, d = t & 127;
    const int c  = (b - 1024) * 2 + cc;
    float count = cnt[c];
    ax[cc][d] = sums[c * 128 + d] / fmaxf(count, 1.0f);
    hx[cc][d] = ch[c * 128 + d];
    __syncthreads();
    float gi[3], gh[3];
#pragma unroll
    for (int g = 0; g < 3; ++g) {
      const float4* wi4 = (const float4*)&gWih[(size_t)(g * 128 + d) * 128];
      const float4* wh4 = (const float4*)&gWhh[(size_t)(g * 128 + d) * 128];
      float si = 0.f, sh = 0.f;
#pragma unroll 8
      for (int e = 0; e < 32; ++e) {
        float4 wv = wi4[e], hv = wh4[e];
        si = fmaf(ax[cc][e*4+0], wv.x, si); si = fmaf(ax[cc][e*4+1], wv.y, si);
        si = fmaf(ax[cc][e*4+2], wv.z, si); si = fmaf(ax[cc][e*4+3], wv.w, si);
        sh = fmaf(hx[cc][e*4+0], hv.x, sh); sh = fmaf(hx[cc][e*4+1], hv.y, sh);
        sh = fmaf(hx[cc][e*4+2], hv.z, sh); sh = fmaf(hx[cc][e*4+3], hv.w, sh);
      }
      gi[g] = si + gbih[g * 128 + d];
      gh[g] = sh + gbhh[g * 128 + d];
    }
    float r = 1.f / (1.f + expf(-(gi[0] + gh[0])));
    float z = 1.f / (1.f + expf(-(gi[1] + gh[1])));
    float nn = tanhf(gi[2] + r * gh[2]);
    float hv = hx[cc][d];
    float nh = (1.f - z) * nn + z * hv;
    float res = (count > 0.f) ? nh : hv;
    ul[cc][d] = res;
    out_uch[c * 128 + d] = res;
    __syncthreads();
    const float4* w4 = (const float4*)&Wp[(size_t)d * 128];
    float s = 0.f;
#pragma unroll 8
    for (int e = 0; e < 32; ++e) {
      float4 wv = w4[e];
      s = fmaf(ul[cc][e*4+0], wv.x, s); s = fmaf(ul[cc][e*4+1], wv.y, s);
      s = fmaf(ul[cc][e*4+2], wv.z, s); s = fmaf(ul[cc][e*4+3], wv.w, s);
    }
    c2n[c * 128 + d] = s + bp[d];
  }
}

// ---------------------------------------------------------------- launch
extern "C" void kernel_launch(void* const* d_in, const int* in_sizes, int n_in,
                              void* d_out, int out_size, void* d_ws, size_t ws_size,
                              hipStream_t stream) {
  const float* x    = (const float*)d_in[0];
  const float* h    = (const float*)d_in[1];
  const float* ch   = (const float*)d_in[2];
  const int*   lab  = (const int*)d_in[4];
  const float* Wq   = (const float*)d_in[8];
  const float* bq   = (const float*)d_in[9];
  const float* Wk   = (const float*)d_in[10];
  const float* bk   = (const float*)d_in[11];
  const float* Wv   = (const float*)d_in[12];
  const float* bv   = (const float*)d_in[13];
  const float* W1   = (const float*)d_in[14];
  const float* b1   = (const float*)d_in[15];
  const float* W2   = (const float*)d_in[16];
  const float* b2   = (const float*)d_in[17];
  const float* gWih = (const float*)d_in[18];
  const float* gbih = (const float*)d_in[19];
  const float* gWhh = (const float*)d_in[20];
  const float* gbhh = (const float*)d_in[21];
  const float* Wp   = (const float*)d_in[22];
  const float* bp   = (const float*)d_in[23];

  float* outp    = (float*)d_out;                 // [4096*128] updated_h
  float* out_uch = outp + 4096 * 128;             // [64*128] updated_cluster_h

  // ---- workspace layout
  f16* comb16 = (f16*)d_ws;                        // 4096*256
  f16* w16    = comb16 + 4096 * 256;               // 655360
  f16* wq16   = w16;                               //  32768
  f16* wk16   = w16 + 32768;
  f16* wv16   = w16 + 65536;                       // 262144 [1024][256]
  f16* w116   = w16 + 327680;                      // 262144 [256][1024]
  f16* w216   = w16 + 589824;                      //  65536 [256][256]
  f16* qf16   = w16 + 655360;                      // 4096*128
  f16* kf16   = qf16 + 4096 * 128;                 // 4096*128
  f16* vt16   = kf16 + 4096 * 128;                 // 1024*4096
  f16* pO     = vt16 + 1024 * 4096;                // 4*1024*4096
  f16* hp16   = pO + (size_t)NSPLIT * 1024 * 4096; // 4096*1024
  f16* y116   = hp16 + (size_t)4096 * 1024;        // 4096*256
  float* pM   = (float*)(y116 + 4096 * 256);       // 4*4*4096
  float* pL   = pM + NSPLIT * 4 * 4096;
  float* sums = pL + NSPLIT * 4 * 4096;            // 8192 (+64 cnt contiguous)
  float* cnt  = sums + 64 * 128;                   // 64
  float* c2n  = cnt + 64;                          // 8192

  const float qscale = 0.17677669529663687f;       // 1/sqrt(32)

  // 1) combined(f16) + weights->f16 + zero(sums,cnt)
  k_prep<<<1697, 256, 0, stream>>>(x, h, Wq, Wk, Wv, W1, W2, comb16, w16, sums);
  // 2) V^T | Q | K projections + segsum, all concurrent
  k_qkv<<<3328, 256, 0, stream>>>(comb16, wq16, wk16, wv16, bq, bk, bv,
                                  qf16, kf16, vt16, h, lab, sums, cnt, qscale);
  // 3) flash attention (split-K, LDS-staged, XCD-pinned combos)
  k_attn_mfma<<<1024, 256, 0, stream>>>(qf16, kf16, vt16, pO, pM, pL);
  // 4) merge -> hp16 [4096][1024]  |  GRU->c2n (also writes out_uch)
  k_mergeplus<<<1056, 256, 0, stream>>>(pO, pM, pL, hp16, sums, cnt, ch,
                                        gWih, gbih, gWhh, gbhh, Wp, bp, out_uch, c2n);
  // 5) MLP1
  k_gemm16<1><<<dim3(64, 4), 256, 0, stream>>>(hp16, w116, b1, nullptr, nullptr, nullptr,
                                               y116, 4096, 1024, 256, 1.0f);
  // 6) MLP2 (cols 128..255) fused with +h resid and +c2n[lab] -> final output
  k_gemm16<3><<<dim3(64, 2), 256, 0, stream>>>(y116, w216 + 128 * 256, b2 + 128, h, lab, c2n,
                                               outp, 4096, 256, 128, 1.0f);
}